// Round 1
// baseline (1377.497 us; speedup 1.0000x reference)
//
#include <hip/hip_runtime.h>
#include <hip/hip_bf16.h>

// ---------------------------------------------------------------------------
// GCN: 3x [H = X@W ; agg[dst] += H[src]*dinv[src]*dinv[dst] ; + H*dinv^2 + b ;
//          (ReLU)] -> mean-pool per graph -> FC 64->2
// Strategy: build CSR (dst-sorted edges) once per launch to make aggregation
// an atomic-free gather; fp32 everywhere to match reference numerics.
// ---------------------------------------------------------------------------

#define THREADS 256

__global__ __launch_bounds__(THREADS) void zero_counts(int* counts, int n) {
    int i = blockIdx.x * THREADS + threadIdx.x;
    if (i < n) counts[i] = 0;
}

__global__ __launch_bounds__(THREADS) void hist_kernel(const int* __restrict__ dst,
                                                       int* __restrict__ counts, int E) {
    int e = blockIdx.x * THREADS + threadIdx.x;
    if (e < E) atomicAdd(&counts[dst[e]], 1);
}

// block-level exclusive scan of counts -> row_start (partial), block sums -> bsum
__global__ __launch_bounds__(THREADS) void scan_block(const int* __restrict__ counts,
                                                      int* __restrict__ row_start,
                                                      int* __restrict__ bsum, int n) {
    __shared__ int lds[THREADS];
    int i = blockIdx.x * THREADS + threadIdx.x;
    int v = (i < n) ? counts[i] : 0;
    lds[threadIdx.x] = v;
    __syncthreads();
    for (int off = 1; off < THREADS; off <<= 1) {
        int t = (threadIdx.x >= off) ? lds[threadIdx.x - off] : 0;
        __syncthreads();
        lds[threadIdx.x] += t;
        __syncthreads();
    }
    if (i < n) row_start[i] = lds[threadIdx.x] - v;  // exclusive
    if (threadIdx.x == THREADS - 1) bsum[blockIdx.x] = lds[THREADS - 1];
}

// single-block exclusive scan of bsum (nb <= 512), in place
__global__ __launch_bounds__(512) void scan_top(int* bsum, int nb) {
    __shared__ int lds[512];
    int v = (threadIdx.x < nb) ? bsum[threadIdx.x] : 0;
    lds[threadIdx.x] = v;
    __syncthreads();
    for (int off = 1; off < 512; off <<= 1) {
        int t = (threadIdx.x >= off) ? lds[threadIdx.x - off] : 0;
        __syncthreads();
        lds[threadIdx.x] += t;
        __syncthreads();
    }
    if (threadIdx.x < nb) bsum[threadIdx.x] = lds[threadIdx.x] - v;  // exclusive
}

__global__ __launch_bounds__(THREADS) void scan_fix(int* __restrict__ row_start,
                                                    const int* __restrict__ bsum,
                                                    const int* __restrict__ counts,
                                                    float* __restrict__ dinv,
                                                    int* __restrict__ cursor, int n, int E) {
    int i = blockIdx.x * THREADS + threadIdx.x;
    if (i < n) {
        int rs = row_start[i] + bsum[blockIdx.x];
        row_start[i] = rs;
        cursor[i] = rs;
        dinv[i] = rsqrtf(1.0f + (float)counts[i]);  // deg = 1 + in-degree (self-loop)
    }
    if (blockIdx.x == 0 && threadIdx.x == 0) row_start[n] = E;
}

__global__ __launch_bounds__(THREADS) void fill_kernel(const int* __restrict__ src,
                                                       const int* __restrict__ dst,
                                                       int* __restrict__ cursor,
                                                       int* __restrict__ esrc, int E) {
    int e = blockIdx.x * THREADS + threadIdx.x;
    if (e < E) {
        int d = dst[e];
        int p = atomicAdd(&cursor[d], 1);
        esrc[p] = src[e];
    }
}

// H[n x C] = X[n x 128] @ W[128 x C]   (row-major). 64 rows per block.
template <int C>
__global__ __launch_bounds__(THREADS) void gemm_kernel(const float* __restrict__ X,
                                                       const float* __restrict__ W,
                                                       float* __restrict__ H, int n) {
    constexpr int CG = C / 8;     // col groups: 16 (C=128) or 8 (C=64)
    constexpr int RG = 256 / CG;  // row groups: 16 or 32
    constexpr int R = 64 / RG;    // rows per thread: 4 or 2
    __shared__ float Xs[64][132];  // pad 132: X-read is 2-way conflict max (free)
    __shared__ float Ws[128][C];
    int row0 = blockIdx.x * 64;
    int maxr = n - row0;
    if (maxr > 64) maxr = 64;
    for (int i = threadIdx.x; i < 128 * C; i += THREADS) Ws[i / C][i % C] = W[i];
    const float4* X4 = (const float4*)(X + (size_t)row0 * 128);
    for (int i = threadIdx.x; i < maxr * 32; i += THREADS) {
        float4 v = X4[i];
        ((float4*)&Xs[i >> 5][0])[i & 31] = v;
    }
    __syncthreads();
    int cg = threadIdx.x % CG;
    int rg = threadIdx.x / CG;
    float acc[R][8];
#pragma unroll
    for (int r = 0; r < R; ++r)
#pragma unroll
        for (int j = 0; j < 8; ++j) acc[r][j] = 0.0f;
#pragma unroll 4
    for (int k = 0; k < 128; ++k) {
        float wv[8];
#pragma unroll
        for (int j = 0; j < 8; ++j) wv[j] = Ws[k][cg + j * CG];  // conflict-free (consecutive c)
#pragma unroll
        for (int r = 0; r < R; ++r) {
            float xv = Xs[rg * R + r][k];
#pragma unroll
            for (int j = 0; j < 8; ++j) acc[r][j] = fmaf(xv, wv[j], acc[r][j]);
        }
    }
#pragma unroll
    for (int r = 0; r < R; ++r) {
        int row = rg * R + r;
        if (row < maxr) {
            float* o = H + (size_t)(row0 + row) * C;
#pragma unroll
            for (int j = 0; j < 8; ++j) o[cg + j * CG] = acc[r][j];
        }
    }
}

// agg[i][c] = sum_{e: dst=i} H[src_e][c]*dinv[src]*dinv[i] + H[i][c]*dinv[i]^2 + b[c]
template <int C, bool RELU>
__global__ __launch_bounds__(THREADS) void agg_kernel(const float* __restrict__ H,
                                                      const int* __restrict__ row_start,
                                                      const int* __restrict__ esrc,
                                                      const float* __restrict__ dinv,
                                                      const float* __restrict__ bias,
                                                      float* __restrict__ out, int n) {
    constexpr int NPB = THREADS / C;
    int node = blockIdx.x * NPB + threadIdx.x / C;
    int c = threadIdx.x % C;
    if (node >= n) return;
    float di = dinv[node];
    int s = row_start[node], e = row_start[node + 1];
    float acc = H[(size_t)node * C + c] * (di * di);  // self-loop message
    for (int i = s; i < e; ++i) {
        int sc = esrc[i];
        acc = fmaf(H[(size_t)sc * C + c] * dinv[sc], di, acc);
    }
    acc += bias[c];
    if (RELU) acc = fmaxf(acc, 0.0f);
    out[(size_t)node * C + c] = acc;
}

__device__ __forceinline__ int dev_lower_bound(const int* a, int n, int key) {
    int lo = 0, hi = n;
    while (lo < hi) {
        int mid = (lo + hi) >> 1;
        if (a[mid] < key) lo = mid + 1;
        else hi = mid;
    }
    return lo;
}

// one block per graph; batch is sorted; mean over node range
__global__ __launch_bounds__(THREADS) void pool_kernel(const float* __restrict__ H3,
                                                       const int* __restrict__ batch, int n,
                                                       float* __restrict__ gmean) {
    int g = blockIdx.x;
    int lo = dev_lower_bound(batch, n, g);
    int hi = dev_lower_bound(batch, n, g + 1);
    int c = threadIdx.x & 63;
    int sub = threadIdx.x >> 6;  // 4 sub-accumulators
    float acc = 0.0f;
    for (int i = lo + sub; i < hi; i += 4) acc += H3[(size_t)i * 64 + c];
    __shared__ float red[4][64];
    red[sub][c] = acc;
    __syncthreads();
    if (sub == 0) {
        float s = red[0][c] + red[1][c] + red[2][c] + red[3][c];
        float cnt = (float)(hi - lo);
        gmean[g * 64 + c] = s / fmaxf(cnt, 1.0f);
    }
}

__global__ __launch_bounds__(128) void fc_kernel(const float* __restrict__ gmean,
                                                 const float* __restrict__ Wfc,
                                                 const float* __restrict__ bfc,
                                                 float* __restrict__ out) {
    int t = threadIdx.x;
    if (t < 128) {
        int g = t >> 1, cls = t & 1;
        float acc = bfc[cls];
        for (int c = 0; c < 64; ++c) acc = fmaf(gmean[g * 64 + c], Wfc[c * 2 + cls], acc);
        out[g * 2 + cls] = acc;
    }
}

extern "C" void kernel_launch(void* const* d_in, const int* in_sizes, int n_in,
                              void* d_out, int out_size, void* d_ws, size_t ws_size,
                              hipStream_t stream) {
    const float* x    = (const float*)d_in[0];
    const int*   ei   = (const int*)d_in[1];
    const int*   batch= (const int*)d_in[2];
    const float* W1   = (const float*)d_in[3];
    const float* b1   = (const float*)d_in[4];
    const float* W2   = (const float*)d_in[5];
    const float* b2   = (const float*)d_in[6];
    const float* W3   = (const float*)d_in[7];
    const float* b3   = (const float*)d_in[8];
    const float* Wfc  = (const float*)d_in[9];
    const float* bfc  = (const float*)d_in[10];
    float* out = (float*)d_out;

    const int N = in_sizes[2];        // 100000
    const int E = in_sizes[1] / 2;    // 1600000
    const int* esrc_in = ei;          // edge_index[0]
    const int* edst_in = ei + E;      // edge_index[1]

    // workspace layout
    float* bufA      = (float*)d_ws;                 // N*128 f32
    float* bufB      = bufA + (size_t)N * 128;       // N*128 f32
    int*   counts    = (int*)(bufB + (size_t)N * 128);
    int*   row_start = counts + N;                   // N+1
    int*   cursor    = row_start + (N + 1);          // N
    float* dinv      = (float*)(cursor + N);         // N
    int*   esrc      = (int*)(dinv + N);             // E
    int*   bsum      = esrc + E;                     // 512
    float* gmean     = (float*)(bsum + 512);         // 64*64

    const int NB = (N + THREADS - 1) / THREADS;      // 391
    const int EB = (E + THREADS - 1) / THREADS;      // 6250

    // ---- CSR build (once; reused by all 3 layers) ----
    zero_counts<<<NB, THREADS, 0, stream>>>(counts, N);
    hist_kernel<<<EB, THREADS, 0, stream>>>(edst_in, counts, E);
    scan_block<<<NB, THREADS, 0, stream>>>(counts, row_start, bsum, N);
    scan_top<<<1, 512, 0, stream>>>(bsum, NB);
    scan_fix<<<NB, THREADS, 0, stream>>>(row_start, bsum, counts, dinv, cursor, N, E);
    fill_kernel<<<EB, THREADS, 0, stream>>>(esrc_in, edst_in, cursor, esrc, E);

    const int GB = (N + 63) / 64;  // gemm blocks (64 rows each)

    // ---- layer 1: H1 = x@W1 -> bufA ; agg+b1+relu -> bufB ----
    gemm_kernel<128><<<GB, THREADS, 0, stream>>>(x, W1, bufA, N);
    agg_kernel<128, true><<<(N + 1) / 2, THREADS, 0, stream>>>(bufA, row_start, esrc, dinv, b1, bufB, N);

    // ---- layer 2: H2 = bufB@W2 -> bufA ; agg+b2+relu -> bufB ----
    gemm_kernel<128><<<GB, THREADS, 0, stream>>>(bufB, W2, bufA, N);
    agg_kernel<128, true><<<(N + 1) / 2, THREADS, 0, stream>>>(bufA, row_start, esrc, dinv, b2, bufB, N);

    // ---- layer 3: H3 = bufB@W3 -> bufA (C=64) ; agg+b3 (no relu) -> bufB ----
    gemm_kernel<64><<<GB, THREADS, 0, stream>>>(bufB, W3, bufA, N);
    agg_kernel<64, false><<<(N + 3) / 4, THREADS, 0, stream>>>(bufA, row_start, esrc, dinv, b3, bufB, N);

    // ---- pool + fc ----
    pool_kernel<<<64, THREADS, 0, stream>>>(bufB, batch, N, gmean);
    fc_kernel<<<1, 128, 0, stream>>>(gmean, Wfc, bfc, out);
}

// Round 2
// 824.046 us; speedup vs baseline: 1.6716x; 1.6716x over previous
//
#include <hip/hip_runtime.h>
#include <hip/hip_bf16.h>

// ---------------------------------------------------------------------------
// GCN: 3x [Hs = (X@W)*dinv ; out = dinv*(sum_{e:dst=i} Hs[src] + Hs[i]) + b ;
//          (ReLU)] -> mean-pool per graph -> FC 64->2
// CSR (dst-sorted edges) built once per launch -> atomic-free gather agg.
// R2: float4 gathers + edge unroll (MLP), dinv folded into GEMM epilogue,
//     GEMM K-tiled (25.6KB LDS -> ~6 blocks/CU) with b128-only LDS reads.
// ---------------------------------------------------------------------------

#define THREADS 256

__global__ __launch_bounds__(THREADS) void zero_counts(int* counts, int n) {
    int i = blockIdx.x * THREADS + threadIdx.x;
    if (i < n) counts[i] = 0;
}

__global__ __launch_bounds__(THREADS) void hist_kernel(const int* __restrict__ dst,
                                                       int* __restrict__ counts, int E) {
    int e = blockIdx.x * THREADS + threadIdx.x;
    if (e < E) atomicAdd(&counts[dst[e]], 1);
}

__global__ __launch_bounds__(THREADS) void scan_block(const int* __restrict__ counts,
                                                      int* __restrict__ row_start,
                                                      int* __restrict__ bsum, int n) {
    __shared__ int lds[THREADS];
    int i = blockIdx.x * THREADS + threadIdx.x;
    int v = (i < n) ? counts[i] : 0;
    lds[threadIdx.x] = v;
    __syncthreads();
    for (int off = 1; off < THREADS; off <<= 1) {
        int t = (threadIdx.x >= off) ? lds[threadIdx.x - off] : 0;
        __syncthreads();
        lds[threadIdx.x] += t;
        __syncthreads();
    }
    if (i < n) row_start[i] = lds[threadIdx.x] - v;  // exclusive
    if (threadIdx.x == THREADS - 1) bsum[blockIdx.x] = lds[THREADS - 1];
}

__global__ __launch_bounds__(512) void scan_top(int* bsum, int nb) {
    __shared__ int lds[512];
    int v = (threadIdx.x < nb) ? bsum[threadIdx.x] : 0;
    lds[threadIdx.x] = v;
    __syncthreads();
    for (int off = 1; off < 512; off <<= 1) {
        int t = (threadIdx.x >= off) ? lds[threadIdx.x - off] : 0;
        __syncthreads();
        lds[threadIdx.x] += t;
        __syncthreads();
    }
    if (threadIdx.x < nb) bsum[threadIdx.x] = lds[threadIdx.x] - v;  // exclusive
}

__global__ __launch_bounds__(THREADS) void scan_fix(int* __restrict__ row_start,
                                                    const int* __restrict__ bsum,
                                                    const int* __restrict__ counts,
                                                    float* __restrict__ dinv,
                                                    int* __restrict__ cursor, int n, int E) {
    int i = blockIdx.x * THREADS + threadIdx.x;
    if (i < n) {
        int rs = row_start[i] + bsum[blockIdx.x];
        row_start[i] = rs;
        cursor[i] = rs;
        dinv[i] = rsqrtf(1.0f + (float)counts[i]);  // deg = 1 + in-degree (self-loop)
    }
    if (blockIdx.x == 0 && threadIdx.x == 0) row_start[n] = E;
}

__global__ __launch_bounds__(THREADS) void fill_kernel(const int* __restrict__ src,
                                                       const int* __restrict__ dst,
                                                       int* __restrict__ cursor,
                                                       int* __restrict__ esrc, int E) {
    int e = blockIdx.x * THREADS + threadIdx.x;
    if (e < E) {
        int d = dst[e];
        int p = atomicAdd(&cursor[d], 1);
        esrc[p] = src[e];
    }
}

// Hs[n x C] = (X[n x 128] @ W[128 x C]) * dinv[row].  64 rows per block,
// K tiled by 32. LDS = 64x36 (X) + 32xC (W) = 25.6KB (C=128) -> ~6 blocks/CU.
template <int C>
__global__ __launch_bounds__(THREADS) void gemm_kernel(const float* __restrict__ X,
                                                       const float* __restrict__ W,
                                                       const float* __restrict__ dinv,
                                                       float* __restrict__ Hs, int n) {
    constexpr int CG = C / 8;     // col groups (8 contiguous cols each): 16 or 8
    constexpr int RG = 256 / CG;  // row groups: 16 or 32
    constexpr int R = 64 / RG;    // rows per thread: 4 or 2
    __shared__ float Xs[64][36];  // 32-k tile, pad to 36 (144B rows, 16B aligned)
    __shared__ float Ws[32][C];
    int row0 = blockIdx.x * 64;
    int maxr = n - row0;
    if (maxr > 64) maxr = 64;
    int cg = threadIdx.x % CG;
    int rg = threadIdx.x / CG;
    float acc[R][8];
#pragma unroll
    for (int r = 0; r < R; ++r)
#pragma unroll
        for (int j = 0; j < 8; ++j) acc[r][j] = 0.0f;

    for (int kt = 0; kt < 4; ++kt) {
        if (kt) __syncthreads();
        // stage X tile: 64 rows x 32 cols (cols kt*32..) -> 512 float4
        const float* Xbase = X + (size_t)row0 * 128 + kt * 32;
        for (int i = threadIdx.x; i < 512; i += THREADS) {
            int r = i >> 3, f = i & 7;
            float4 v = make_float4(0.f, 0.f, 0.f, 0.f);
            if (r < maxr) v = *(const float4*)(Xbase + (size_t)r * 128 + f * 4);
            *(float4*)&Xs[r][f * 4] = v;
        }
        // stage W tile: 32 x C
        const float4* Wbase = (const float4*)(W + (size_t)kt * 32 * C);
        for (int i = threadIdx.x; i < 32 * C / 4; i += THREADS)
            ((float4*)&Ws[0][0])[i] = Wbase[i];
        __syncthreads();
#pragma unroll
        for (int kk = 0; kk < 32; kk += 4) {
            float4 xr[R];
#pragma unroll
            for (int r = 0; r < R; ++r) xr[r] = *(const float4*)&Xs[rg * R + r][kk];
#pragma unroll
            for (int j = 0; j < 4; ++j) {
                float4 w0 = *(const float4*)&Ws[kk + j][cg * 8];
                float4 w1 = *(const float4*)&Ws[kk + j][cg * 8 + 4];
#pragma unroll
                for (int r = 0; r < R; ++r) {
                    float xv = (&xr[r].x)[j];
                    acc[r][0] = fmaf(xv, w0.x, acc[r][0]);
                    acc[r][1] = fmaf(xv, w0.y, acc[r][1]);
                    acc[r][2] = fmaf(xv, w0.z, acc[r][2]);
                    acc[r][3] = fmaf(xv, w0.w, acc[r][3]);
                    acc[r][4] = fmaf(xv, w1.x, acc[r][4]);
                    acc[r][5] = fmaf(xv, w1.y, acc[r][5]);
                    acc[r][6] = fmaf(xv, w1.z, acc[r][6]);
                    acc[r][7] = fmaf(xv, w1.w, acc[r][7]);
                }
            }
        }
    }
    // epilogue: scale row by dinv[row] (pre-scale for the gather), store 2xfloat4
#pragma unroll
    for (int r = 0; r < R; ++r) {
        int row = rg * R + r;
        if (row < maxr) {
            float dv = dinv[row0 + row];
            float* o = Hs + (size_t)(row0 + row) * C + cg * 8;
            float4 o0 = make_float4(acc[r][0] * dv, acc[r][1] * dv, acc[r][2] * dv, acc[r][3] * dv);
            float4 o1 = make_float4(acc[r][4] * dv, acc[r][5] * dv, acc[r][6] * dv, acc[r][7] * dv);
            *(float4*)o = o0;
            *(float4*)(o + 4) = o1;
        }
    }
}

// out[i] = dinv[i]*(sum_{e:dst=i} Hs[src_e] + Hs[i]) + b ; optional ReLU.
// float4 per lane; edge loop unrolled x8/x4 for MLP.
template <int C, bool RELU>
__global__ __launch_bounds__(THREADS) void agg_kernel(const float* __restrict__ Hs,
                                                      const int* __restrict__ row_start,
                                                      const int* __restrict__ esrc,
                                                      const float* __restrict__ dinv,
                                                      const float* __restrict__ bias,
                                                      float* __restrict__ out, int n) {
    constexpr int LPN = C / 4;          // lanes per node: 32 (C=128) or 16 (C=64)
    constexpr int NPB = THREADS / LPN;  // nodes per block: 8 or 16
    int node = blockIdx.x * NPB + threadIdx.x / LPN;
    int lane = threadIdx.x % LPN;
    if (node >= n) return;
    const float4* H4 = (const float4*)Hs;
    float di = dinv[node];
    int s = row_start[node], e = row_start[node + 1];
    float4 a = H4[(size_t)node * LPN + lane];  // self term Hs[i]
    float acx = a.x, acy = a.y, acz = a.z, acw = a.w;
    int i = s;
    for (; i + 8 <= e; i += 8) {
        int s0 = esrc[i], s1 = esrc[i + 1], s2 = esrc[i + 2], s3 = esrc[i + 3];
        int s4 = esrc[i + 4], s5 = esrc[i + 5], s6 = esrc[i + 6], s7 = esrc[i + 7];
        float4 v0 = H4[(size_t)s0 * LPN + lane];
        float4 v1 = H4[(size_t)s1 * LPN + lane];
        float4 v2 = H4[(size_t)s2 * LPN + lane];
        float4 v3 = H4[(size_t)s3 * LPN + lane];
        float4 v4 = H4[(size_t)s4 * LPN + lane];
        float4 v5 = H4[(size_t)s5 * LPN + lane];
        float4 v6 = H4[(size_t)s6 * LPN + lane];
        float4 v7 = H4[(size_t)s7 * LPN + lane];
        acx += ((v0.x + v1.x) + (v2.x + v3.x)) + ((v4.x + v5.x) + (v6.x + v7.x));
        acy += ((v0.y + v1.y) + (v2.y + v3.y)) + ((v4.y + v5.y) + (v6.y + v7.y));
        acz += ((v0.z + v1.z) + (v2.z + v3.z)) + ((v4.z + v5.z) + (v6.z + v7.z));
        acw += ((v0.w + v1.w) + (v2.w + v3.w)) + ((v4.w + v5.w) + (v6.w + v7.w));
    }
    for (; i + 4 <= e; i += 4) {
        int s0 = esrc[i], s1 = esrc[i + 1], s2 = esrc[i + 2], s3 = esrc[i + 3];
        float4 v0 = H4[(size_t)s0 * LPN + lane];
        float4 v1 = H4[(size_t)s1 * LPN + lane];
        float4 v2 = H4[(size_t)s2 * LPN + lane];
        float4 v3 = H4[(size_t)s3 * LPN + lane];
        acx += (v0.x + v1.x) + (v2.x + v3.x);
        acy += (v0.y + v1.y) + (v2.y + v3.y);
        acz += (v0.z + v1.z) + (v2.z + v3.z);
        acw += (v0.w + v1.w) + (v2.w + v3.w);
    }
    for (; i < e; ++i) {
        float4 v = H4[(size_t)esrc[i] * LPN + lane];
        acx += v.x; acy += v.y; acz += v.z; acw += v.w;
    }
    float4 b4 = ((const float4*)bias)[lane];
    float ox = fmaf(di, acx, b4.x);
    float oy = fmaf(di, acy, b4.y);
    float oz = fmaf(di, acz, b4.z);
    float ow = fmaf(di, acw, b4.w);
    if (RELU) {
        ox = fmaxf(ox, 0.f); oy = fmaxf(oy, 0.f);
        oz = fmaxf(oz, 0.f); ow = fmaxf(ow, 0.f);
    }
    ((float4*)out)[(size_t)node * LPN + lane] = make_float4(ox, oy, oz, ow);
}

__device__ __forceinline__ int dev_lower_bound(const int* a, int n, int key) {
    int lo = 0, hi = n;
    while (lo < hi) {
        int mid = (lo + hi) >> 1;
        if (a[mid] < key) lo = mid + 1;
        else hi = mid;
    }
    return lo;
}

__global__ __launch_bounds__(THREADS) void pool_kernel(const float* __restrict__ H3,
                                                       const int* __restrict__ batch, int n,
                                                       float* __restrict__ gmean) {
    int g = blockIdx.x;
    int lo = dev_lower_bound(batch, n, g);
    int hi = dev_lower_bound(batch, n, g + 1);
    int c = threadIdx.x & 63;
    int sub = threadIdx.x >> 6;  // 4 sub-accumulators
    float acc = 0.0f;
    for (int i = lo + sub; i < hi; i += 4) acc += H3[(size_t)i * 64 + c];
    __shared__ float red[4][64];
    red[sub][c] = acc;
    __syncthreads();
    if (sub == 0) {
        float s = red[0][c] + red[1][c] + red[2][c] + red[3][c];
        float cnt = (float)(hi - lo);
        gmean[g * 64 + c] = s / fmaxf(cnt, 1.0f);
    }
}

__global__ __launch_bounds__(128) void fc_kernel(const float* __restrict__ gmean,
                                                 const float* __restrict__ Wfc,
                                                 const float* __restrict__ bfc,
                                                 float* __restrict__ out) {
    int t = threadIdx.x;
    if (t < 128) {
        int g = t >> 1, cls = t & 1;
        float acc = bfc[cls];
        for (int c = 0; c < 64; ++c) acc = fmaf(gmean[g * 64 + c], Wfc[c * 2 + cls], acc);
        out[g * 2 + cls] = acc;
    }
}

extern "C" void kernel_launch(void* const* d_in, const int* in_sizes, int n_in,
                              void* d_out, int out_size, void* d_ws, size_t ws_size,
                              hipStream_t stream) {
    const float* x    = (const float*)d_in[0];
    const int*   ei   = (const int*)d_in[1];
    const int*   batch= (const int*)d_in[2];
    const float* W1   = (const float*)d_in[3];
    const float* b1   = (const float*)d_in[4];
    const float* W2   = (const float*)d_in[5];
    const float* b2   = (const float*)d_in[6];
    const float* W3   = (const float*)d_in[7];
    const float* b3   = (const float*)d_in[8];
    const float* Wfc  = (const float*)d_in[9];
    const float* bfc  = (const float*)d_in[10];
    float* out = (float*)d_out;

    const int N = in_sizes[2];        // 100000
    const int E = in_sizes[1] / 2;    // 1600000
    const int* esrc_in = ei;          // edge_index[0]
    const int* edst_in = ei + E;      // edge_index[1]

    // workspace layout
    float* bufA      = (float*)d_ws;                 // N*128 f32
    float* bufB      = bufA + (size_t)N * 128;       // N*128 f32
    int*   counts    = (int*)(bufB + (size_t)N * 128);
    int*   row_start = counts + N;                   // N+1
    int*   cursor    = row_start + (N + 1);          // N
    float* dinv      = (float*)(cursor + N);         // N
    int*   esrc      = (int*)(dinv + N);             // E
    int*   bsum      = esrc + E;                     // 512
    float* gmean     = (float*)(bsum + 512);         // 64*64

    const int NB = (N + THREADS - 1) / THREADS;      // 391
    const int EB = (E + THREADS - 1) / THREADS;      // 6250

    // ---- CSR build (once; reused by all 3 layers). Produces dinv too. ----
    zero_counts<<<NB, THREADS, 0, stream>>>(counts, N);
    hist_kernel<<<EB, THREADS, 0, stream>>>(edst_in, counts, E);
    scan_block<<<NB, THREADS, 0, stream>>>(counts, row_start, bsum, N);
    scan_top<<<1, 512, 0, stream>>>(bsum, NB);
    scan_fix<<<NB, THREADS, 0, stream>>>(row_start, bsum, counts, dinv, cursor, N, E);
    fill_kernel<<<EB, THREADS, 0, stream>>>(esrc_in, edst_in, cursor, esrc, E);

    const int GB = (N + 63) / 64;  // gemm blocks (64 rows each)

    // ---- layer 1 ----
    gemm_kernel<128><<<GB, THREADS, 0, stream>>>(x, W1, dinv, bufA, N);
    agg_kernel<128, true><<<(N + 7) / 8, THREADS, 0, stream>>>(bufA, row_start, esrc, dinv, b1, bufB, N);

    // ---- layer 2 ----
    gemm_kernel<128><<<GB, THREADS, 0, stream>>>(bufB, W2, dinv, bufA, N);
    agg_kernel<128, true><<<(N + 7) / 8, THREADS, 0, stream>>>(bufA, row_start, esrc, dinv, b2, bufB, N);

    // ---- layer 3 (C=64, no relu) ----
    gemm_kernel<64><<<GB, THREADS, 0, stream>>>(bufB, W3, dinv, bufA, N);
    agg_kernel<64, false><<<(N + 15) / 16, THREADS, 0, stream>>>(bufA, row_start, esrc, dinv, b3, bufB, N);

    // ---- pool + fc ----
    pool_kernel<<<64, THREADS, 0, stream>>>(bufB, batch, N, gmean);
    fc_kernel<<<1, 128, 0, stream>>>(gmean, Wfc, bfc, out);
}

// Round 3
// 593.433 us; speedup vs baseline: 2.3212x; 1.3886x over previous
//
#include <hip/hip_runtime.h>
#include <hip/hip_bf16.h>

// ---------------------------------------------------------------------------
// GCN: 3x [Hs = bf16((X@W)*dinv) ; out = dinv*(sum_{e:dst=i} Hs[src] + Hs[i]) + b ;
//          (ReLU)] -> mean-pool per graph -> FC 64->2
// R3: bucketed CSR build (kills scatter write-amplification seen in R2:
//     fill WRITE_SIZE 105MB for 6.4MB payload), bf16 Hs gather (halves agg
//     bytes; fp32 accumulate; RNE rounding so pooling averages the error out).
// ---------------------------------------------------------------------------

#define THREADS 256
#define BSHIFT 9
#define BSIZE 512   // dsts per bucket

__device__ __forceinline__ unsigned f2bf(float f) {  // fp32 -> bf16 bits, RNE
    unsigned u = __float_as_uint(f);
    return (u + 0x7fffu + ((u >> 16) & 1u)) >> 16;
}

__device__ __forceinline__ void bf8_acc(uint4 v, float* ac) {
    ac[0] += __uint_as_float(v.x << 16);
    ac[1] += __uint_as_float(v.x & 0xffff0000u);
    ac[2] += __uint_as_float(v.y << 16);
    ac[3] += __uint_as_float(v.y & 0xffff0000u);
    ac[4] += __uint_as_float(v.z << 16);
    ac[5] += __uint_as_float(v.z & 0xffff0000u);
    ac[6] += __uint_as_float(v.w << 16);
    ac[7] += __uint_as_float(v.w & 0xffff0000u);
}

// ---- bucketed CSR build ----------------------------------------------------

__global__ __launch_bounds__(512) void zero_btotal(int* btotal, int nbuck) {
    if ((int)threadIdx.x < nbuck) btotal[threadIdx.x] = 0;
}

__global__ __launch_bounds__(THREADS) void bucket_count(const int* __restrict__ dst,
                                                        int* __restrict__ btotal,
                                                        int E, int nbuck) {
    __shared__ int cnt[BSIZE];
    for (int i = threadIdx.x; i < nbuck; i += THREADS) cnt[i] = 0;
    __syncthreads();
    for (int e = blockIdx.x * THREADS + threadIdx.x; e < E; e += gridDim.x * THREADS)
        atomicAdd(&cnt[dst[e] >> BSHIFT], 1);
    __syncthreads();
    for (int i = threadIdx.x; i < nbuck; i += THREADS) {
        int c = cnt[i];
        if (c) atomicAdd(&btotal[i], c);
    }
}

__global__ __launch_bounds__(512) void bucket_scan(const int* __restrict__ btotal,
                                                   int* __restrict__ bbase,
                                                   int* __restrict__ bcursor,
                                                   int nbuck, int E) {
    __shared__ int lds[512];
    int t = threadIdx.x;
    int v = (t < nbuck) ? btotal[t] : 0;
    lds[t] = v;
    __syncthreads();
    for (int off = 1; off < 512; off <<= 1) {
        int tv = (t >= off) ? lds[t - off] : 0;
        __syncthreads();
        lds[t] += tv;
        __syncthreads();
    }
    if (t < nbuck) {
        int excl = lds[t] - v;
        bbase[t] = excl;
        bcursor[t] = excl;
    }
    if (t == 0) bbase[nbuck] = E;
}

// chunk = 2048 edges/block; LDS ranks + one bulk cursor bump per (chunk,bucket).
__global__ __launch_bounds__(THREADS) void bucket_scatter(const int* __restrict__ src,
                                                          const int* __restrict__ dst,
                                                          int* __restrict__ bcursor,
                                                          int2* __restrict__ pairs, int E) {
    __shared__ int cnt[BSIZE];
    __shared__ int base[BSIZE];
    for (int i = threadIdx.x; i < BSIZE; i += THREADS) cnt[i] = 0;
    __syncthreads();
    int e0 = blockIdx.x * 2048;
    int myb[8], myrank[8], mysrc[8], mydst[8];
#pragma unroll
    for (int j = 0; j < 8; ++j) {
        int e = e0 + j * THREADS + threadIdx.x;
        myb[j] = -1;
        if (e < E) {
            int d = dst[e];
            mysrc[j] = src[e];
            mydst[j] = d;
            myb[j] = d >> BSHIFT;
            myrank[j] = atomicAdd(&cnt[myb[j]], 1);
        }
    }
    __syncthreads();
    for (int i = threadIdx.x; i < BSIZE; i += THREADS) {
        int c = cnt[i];
        base[i] = c ? atomicAdd(&bcursor[i], c) : 0;
    }
    __syncthreads();
#pragma unroll
    for (int j = 0; j < 8; ++j)
        if (myb[j] >= 0) pairs[(size_t)base[myb[j]] + myrank[j]] = make_int2(mysrc[j], mydst[j]);
}

// one block per bucket: local count/scan -> row_start+dinv; local cursor -> esrc.
// All writes land in this block's own region: full-line, single-XCD.
__global__ __launch_bounds__(512) void bucket_fill(const int2* __restrict__ pairs,
                                                   const int* __restrict__ bbase,
                                                   int* __restrict__ row_start,
                                                   float* __restrict__ dinv,
                                                   int* __restrict__ esrc,
                                                   int N, int E, int nbuck) {
    __shared__ int cnt[BSIZE];
    __shared__ int scn[BSIZE];
    int b = blockIdx.x, t = threadIdx.x;
    int s = bbase[b], e = bbase[b + 1];
    cnt[t] = 0;
    __syncthreads();
    for (int i = s + t; i < e; i += 512) atomicAdd(&cnt[pairs[i].y & (BSIZE - 1)], 1);
    __syncthreads();
    int v = cnt[t];
    scn[t] = v;
    __syncthreads();
    for (int off = 1; off < 512; off <<= 1) {
        int tv = (t >= off) ? scn[t - off] : 0;
        __syncthreads();
        scn[t] += tv;
        __syncthreads();
    }
    int excl = scn[t] - v;
    int g = (b << BSHIFT) + t;
    if (g < N) {
        row_start[g] = s + excl;
        dinv[g] = rsqrtf(1.0f + (float)v);  // deg = 1 + in-degree (self-loop)
    }
    if (b == nbuck - 1 && t == 0) row_start[N] = E;
    scn[t] = excl;  // reuse as cursor
    __syncthreads();
    for (int i = s + t; i < e; i += 512) {
        int2 p = pairs[i];
        int r = atomicAdd(&scn[p.y & (BSIZE - 1)], 1);
        esrc[s + r] = p.x;
    }
}

// ---- GEMM: Hs[n x C](bf16) = (X[n x 128] @ W[128 x C]) * dinv[row] ---------
template <int C>
__global__ __launch_bounds__(THREADS) void gemm_kernel(const float* __restrict__ X,
                                                       const float* __restrict__ W,
                                                       const float* __restrict__ dinv,
                                                       unsigned* __restrict__ Hs, int n) {
    constexpr int CG = C / 8;     // col groups (8 contiguous cols each): 16 or 8
    constexpr int RG = 256 / CG;  // row groups: 16 or 32
    constexpr int R = 64 / RG;    // rows per thread: 4 or 2
    __shared__ float Xs[64][36];  // 32-k tile, pad to 36
    __shared__ float Ws[32][C];
    int row0 = blockIdx.x * 64;
    int maxr = n - row0;
    if (maxr > 64) maxr = 64;
    int cg = threadIdx.x % CG;
    int rg = threadIdx.x / CG;
    float acc[R][8];
#pragma unroll
    for (int r = 0; r < R; ++r)
#pragma unroll
        for (int j = 0; j < 8; ++j) acc[r][j] = 0.0f;

    for (int kt = 0; kt < 4; ++kt) {
        if (kt) __syncthreads();
        const float* Xbase = X + (size_t)row0 * 128 + kt * 32;
        for (int i = threadIdx.x; i < 512; i += THREADS) {
            int r = i >> 3, f = i & 7;
            float4 v = make_float4(0.f, 0.f, 0.f, 0.f);
            if (r < maxr) v = *(const float4*)(Xbase + (size_t)r * 128 + f * 4);
            *(float4*)&Xs[r][f * 4] = v;
        }
        const float4* Wbase = (const float4*)(W + (size_t)kt * 32 * C);
        for (int i = threadIdx.x; i < 32 * C / 4; i += THREADS)
            ((float4*)&Ws[0][0])[i] = Wbase[i];
        __syncthreads();
#pragma unroll
        for (int kk = 0; kk < 32; kk += 4) {
            float4 xr[R];
#pragma unroll
            for (int r = 0; r < R; ++r) xr[r] = *(const float4*)&Xs[rg * R + r][kk];
#pragma unroll
            for (int j = 0; j < 4; ++j) {
                float4 w0 = *(const float4*)&Ws[kk + j][cg * 8];
                float4 w1 = *(const float4*)&Ws[kk + j][cg * 8 + 4];
#pragma unroll
                for (int r = 0; r < R; ++r) {
                    float xv = (&xr[r].x)[j];
                    acc[r][0] = fmaf(xv, w0.x, acc[r][0]);
                    acc[r][1] = fmaf(xv, w0.y, acc[r][1]);
                    acc[r][2] = fmaf(xv, w0.z, acc[r][2]);
                    acc[r][3] = fmaf(xv, w0.w, acc[r][3]);
                    acc[r][4] = fmaf(xv, w1.x, acc[r][4]);
                    acc[r][5] = fmaf(xv, w1.y, acc[r][5]);
                    acc[r][6] = fmaf(xv, w1.z, acc[r][6]);
                    acc[r][7] = fmaf(xv, w1.w, acc[r][7]);
                }
            }
        }
    }
    // epilogue: scale by dinv, RNE-round to bf16, pack 8ch -> uint4
#pragma unroll
    for (int r = 0; r < R; ++r) {
        int row = rg * R + r;
        if (row < maxr) {
            float dv = dinv[row0 + row];
            uint4 o;
            o.x = f2bf(acc[r][0] * dv) | (f2bf(acc[r][1] * dv) << 16);
            o.y = f2bf(acc[r][2] * dv) | (f2bf(acc[r][3] * dv) << 16);
            o.z = f2bf(acc[r][4] * dv) | (f2bf(acc[r][5] * dv) << 16);
            o.w = f2bf(acc[r][6] * dv) | (f2bf(acc[r][7] * dv) << 16);
            ((uint4*)Hs)[(size_t)(row0 + row) * (C / 8) + cg] = o;
        }
    }
}

// ---- agg: out[i] = dinv[i]*(sum Hs[src] + Hs[i]) + b (fp32 out) ------------
template <int C, bool RELU>
__global__ __launch_bounds__(THREADS) void agg_kernel(const unsigned* __restrict__ Hs,
                                                      const int* __restrict__ row_start,
                                                      const int* __restrict__ esrc,
                                                      const float* __restrict__ dinv,
                                                      const float* __restrict__ bias,
                                                      float* __restrict__ out, int n) {
    constexpr int LPN = C / 8;          // lanes per node (8 bf16 ch per lane)
    constexpr int NPB = THREADS / LPN;  // nodes per block: 16 (C=128) or 32 (C=64)
    int node = blockIdx.x * NPB + threadIdx.x / LPN;
    int lane = threadIdx.x % LPN;
    if (node >= n) return;
    const uint4* H4 = (const uint4*)Hs;
    float di = dinv[node];
    int s = row_start[node], e = row_start[node + 1];
    float ac[8] = {0, 0, 0, 0, 0, 0, 0, 0};
    bf8_acc(H4[(size_t)node * LPN + lane], ac);  // self term
    int i = s;
    for (; i + 8 <= e; i += 8) {
        int s0 = esrc[i], s1 = esrc[i + 1], s2 = esrc[i + 2], s3 = esrc[i + 3];
        int s4 = esrc[i + 4], s5 = esrc[i + 5], s6 = esrc[i + 6], s7 = esrc[i + 7];
        uint4 v0 = H4[(size_t)s0 * LPN + lane];
        uint4 v1 = H4[(size_t)s1 * LPN + lane];
        uint4 v2 = H4[(size_t)s2 * LPN + lane];
        uint4 v3 = H4[(size_t)s3 * LPN + lane];
        uint4 v4 = H4[(size_t)s4 * LPN + lane];
        uint4 v5 = H4[(size_t)s5 * LPN + lane];
        uint4 v6 = H4[(size_t)s6 * LPN + lane];
        uint4 v7 = H4[(size_t)s7 * LPN + lane];
        bf8_acc(v0, ac); bf8_acc(v1, ac); bf8_acc(v2, ac); bf8_acc(v3, ac);
        bf8_acc(v4, ac); bf8_acc(v5, ac); bf8_acc(v6, ac); bf8_acc(v7, ac);
    }
    for (; i + 4 <= e; i += 4) {
        int s0 = esrc[i], s1 = esrc[i + 1], s2 = esrc[i + 2], s3 = esrc[i + 3];
        uint4 v0 = H4[(size_t)s0 * LPN + lane];
        uint4 v1 = H4[(size_t)s1 * LPN + lane];
        uint4 v2 = H4[(size_t)s2 * LPN + lane];
        uint4 v3 = H4[(size_t)s3 * LPN + lane];
        bf8_acc(v0, ac); bf8_acc(v1, ac); bf8_acc(v2, ac); bf8_acc(v3, ac);
    }
    for (; i < e; ++i) bf8_acc(H4[(size_t)esrc[i] * LPN + lane], ac);

    float4 b0 = ((const float4*)bias)[lane * 2];
    float4 b1 = ((const float4*)bias)[lane * 2 + 1];
    float4 o0, o1;
    o0.x = fmaf(di, ac[0], b0.x); o0.y = fmaf(di, ac[1], b0.y);
    o0.z = fmaf(di, ac[2], b0.z); o0.w = fmaf(di, ac[3], b0.w);
    o1.x = fmaf(di, ac[4], b1.x); o1.y = fmaf(di, ac[5], b1.y);
    o1.z = fmaf(di, ac[6], b1.z); o1.w = fmaf(di, ac[7], b1.w);
    if (RELU) {
        o0.x = fmaxf(o0.x, 0.f); o0.y = fmaxf(o0.y, 0.f);
        o0.z = fmaxf(o0.z, 0.f); o0.w = fmaxf(o0.w, 0.f);
        o1.x = fmaxf(o1.x, 0.f); o1.y = fmaxf(o1.y, 0.f);
        o1.z = fmaxf(o1.z, 0.f); o1.w = fmaxf(o1.w, 0.f);
    }
    float4* O = (float4*)out;
    O[(size_t)node * (C / 4) + lane * 2] = o0;
    O[(size_t)node * (C / 4) + lane * 2 + 1] = o1;
}

// ---- pool + fc -------------------------------------------------------------
__device__ __forceinline__ int dev_lower_bound(const int* a, int n, int key) {
    int lo = 0, hi = n;
    while (lo < hi) {
        int mid = (lo + hi) >> 1;
        if (a[mid] < key) lo = mid + 1;
        else hi = mid;
    }
    return lo;
}

__global__ __launch_bounds__(THREADS) void pool_kernel(const float* __restrict__ H3,
                                                       const int* __restrict__ batch, int n,
                                                       float* __restrict__ gmean) {
    int g = blockIdx.x;
    int lo = dev_lower_bound(batch, n, g);
    int hi = dev_lower_bound(batch, n, g + 1);
    int c = threadIdx.x & 63;
    int sub = threadIdx.x >> 6;
    float acc = 0.0f;
    for (int i = lo + sub; i < hi; i += 4) acc += H3[(size_t)i * 64 + c];
    __shared__ float red[4][64];
    red[sub][c] = acc;
    __syncthreads();
    if (sub == 0) {
        float s = red[0][c] + red[1][c] + red[2][c] + red[3][c];
        float cnt = (float)(hi - lo);
        gmean[g * 64 + c] = s / fmaxf(cnt, 1.0f);
    }
}

__global__ __launch_bounds__(128) void fc_kernel(const float* __restrict__ gmean,
                                                 const float* __restrict__ Wfc,
                                                 const float* __restrict__ bfc,
                                                 float* __restrict__ out) {
    int t = threadIdx.x;
    if (t < 128) {
        int g = t >> 1, cls = t & 1;
        float acc = bfc[cls];
        for (int c = 0; c < 64; ++c) acc = fmaf(gmean[g * 64 + c], Wfc[c * 2 + cls], acc);
        out[g * 2 + cls] = acc;
    }
}

extern "C" void kernel_launch(void* const* d_in, const int* in_sizes, int n_in,
                              void* d_out, int out_size, void* d_ws, size_t ws_size,
                              hipStream_t stream) {
    const float* x    = (const float*)d_in[0];
    const int*   ei   = (const int*)d_in[1];
    const int*   batch= (const int*)d_in[2];
    const float* W1   = (const float*)d_in[3];
    const float* b1   = (const float*)d_in[4];
    const float* W2   = (const float*)d_in[5];
    const float* b2   = (const float*)d_in[6];
    const float* W3   = (const float*)d_in[7];
    const float* b3   = (const float*)d_in[8];
    const float* Wfc  = (const float*)d_in[9];
    const float* bfc  = (const float*)d_in[10];
    float* out = (float*)d_out;

    const int N = in_sizes[2];        // 100000
    const int E = in_sizes[1] / 2;    // 1600000
    const int* esrc_in = ei;          // edge_index[0]
    const int* edst_in = ei + E;      // edge_index[1]
    const int nbuck = (N + BSIZE - 1) >> BSHIFT;  // 196

    // workspace layout (~97 MB)
    float*    bufA      = (float*)d_ws;                      // N*128 f32
    unsigned* bufH      = (unsigned*)(bufA + (size_t)N * 128); // N*64 uints (bf16 x2)
    int2*     pairs     = (int2*)(bufH + (size_t)N * 64);    // E
    int*      esrc      = (int*)(pairs + E);                 // E
    int*      row_start = esrc + E;                          // N+1
    float*    dinv      = (float*)(row_start + N + 1);       // N
    int*      btotal    = (int*)(dinv + N);                  // 512
    int*      bbase     = btotal + 512;                      // 513
    int*      bcursor   = bbase + 513;                       // 512
    float*    gmean     = (float*)(bcursor + 512);           // 64*64

    // ---- bucketed CSR build (once; reused by all 3 layers) ----
    zero_btotal<<<1, 512, 0, stream>>>(btotal, nbuck);
    bucket_count<<<512, THREADS, 0, stream>>>(edst_in, btotal, E, nbuck);
    bucket_scan<<<1, 512, 0, stream>>>(btotal, bbase, bcursor, nbuck, E);
    bucket_scatter<<<(E + 2047) / 2048, THREADS, 0, stream>>>(esrc_in, edst_in, bcursor, pairs, E);
    bucket_fill<<<nbuck, 512, 0, stream>>>(pairs, bbase, row_start, dinv, esrc, N, E, nbuck);

    const int GB = (N + 63) / 64;

    // ---- layer 1 ----
    gemm_kernel<128><<<GB, THREADS, 0, stream>>>(x, W1, dinv, bufH, N);
    agg_kernel<128, true><<<(N + 15) / 16, THREADS, 0, stream>>>(bufH, row_start, esrc, dinv, b1, bufA, N);

    // ---- layer 2 ----
    gemm_kernel<128><<<GB, THREADS, 0, stream>>>(bufA, W2, dinv, bufH, N);
    agg_kernel<128, true><<<(N + 15) / 16, THREADS, 0, stream>>>(bufH, row_start, esrc, dinv, b2, bufA, N);

    // ---- layer 3 (C=64, no relu) ----
    gemm_kernel<64><<<GB, THREADS, 0, stream>>>(bufA, W3, dinv, bufH, N);
    agg_kernel<64, false><<<(N + 31) / 32, THREADS, 0, stream>>>(bufH, row_start, esrc, dinv, b3, bufA, N);

    // ---- pool + fc ----
    pool_kernel<<<64, THREADS, 0, stream>>>(bufA, batch, N, gmean);
    fc_kernel<<<1, 128, 0, stream>>>(gmean, Wfc, bfc, out);
}

// Round 4
// 516.009 us; speedup vs baseline: 2.6695x; 1.1500x over previous
//
#include <hip/hip_runtime.h>
#include <hip/hip_bf16.h>

// ---------------------------------------------------------------------------
// GCN: 3x [Hs = bf16((X@W)*dinv) ; out = dinv*(sum_{e:dst=i} Hs[src] + Hs[i]) + b ;
//          (ReLU)] -> mean-pool per graph -> FC 64->2
// R4: two-stage pool (R3 profile: 1-block-per-graph pool was 110us at 2.5%
//     occupancy / 116 GB/s). Stage1: chunked coalesced partial sums + rare
//     fp32 atomics at graph transitions; Stage2: fused mean + FC.
// ---------------------------------------------------------------------------

#define THREADS 256
#define BSHIFT 9
#define BSIZE 512   // dsts per bucket

__device__ __forceinline__ unsigned f2bf(float f) {  // fp32 -> bf16 bits, RNE
    unsigned u = __float_as_uint(f);
    return (u + 0x7fffu + ((u >> 16) & 1u)) >> 16;
}

__device__ __forceinline__ void bf8_acc(uint4 v, float* ac) {
    ac[0] += __uint_as_float(v.x << 16);
    ac[1] += __uint_as_float(v.x & 0xffff0000u);
    ac[2] += __uint_as_float(v.y << 16);
    ac[3] += __uint_as_float(v.y & 0xffff0000u);
    ac[4] += __uint_as_float(v.z << 16);
    ac[5] += __uint_as_float(v.z & 0xffff0000u);
    ac[6] += __uint_as_float(v.w << 16);
    ac[7] += __uint_as_float(v.w & 0xffff0000u);
}

// ---- bucketed CSR build ----------------------------------------------------

__global__ __launch_bounds__(512) void zero_btotal(int* btotal, int nbuck) {
    if ((int)threadIdx.x < nbuck) btotal[threadIdx.x] = 0;
}

__global__ __launch_bounds__(THREADS) void zero_f32(float* p, int n) {
    int i = blockIdx.x * THREADS + threadIdx.x;
    if (i < n) p[i] = 0.0f;
}

__global__ __launch_bounds__(THREADS) void bucket_count(const int* __restrict__ dst,
                                                        int* __restrict__ btotal,
                                                        int E, int nbuck) {
    __shared__ int cnt[BSIZE];
    for (int i = threadIdx.x; i < nbuck; i += THREADS) cnt[i] = 0;
    __syncthreads();
    for (int e = blockIdx.x * THREADS + threadIdx.x; e < E; e += gridDim.x * THREADS)
        atomicAdd(&cnt[dst[e] >> BSHIFT], 1);
    __syncthreads();
    for (int i = threadIdx.x; i < nbuck; i += THREADS) {
        int c = cnt[i];
        if (c) atomicAdd(&btotal[i], c);
    }
}

__global__ __launch_bounds__(512) void bucket_scan(const int* __restrict__ btotal,
                                                   int* __restrict__ bbase,
                                                   int* __restrict__ bcursor,
                                                   int nbuck, int E) {
    __shared__ int lds[512];
    int t = threadIdx.x;
    int v = (t < nbuck) ? btotal[t] : 0;
    lds[t] = v;
    __syncthreads();
    for (int off = 1; off < 512; off <<= 1) {
        int tv = (t >= off) ? lds[t - off] : 0;
        __syncthreads();
        lds[t] += tv;
        __syncthreads();
    }
    if (t < nbuck) {
        int excl = lds[t] - v;
        bbase[t] = excl;
        bcursor[t] = excl;
    }
    if (t == 0) bbase[nbuck] = E;
}

// chunk = 2048 edges/block; LDS ranks + one bulk cursor bump per (chunk,bucket).
__global__ __launch_bounds__(THREADS) void bucket_scatter(const int* __restrict__ src,
                                                          const int* __restrict__ dst,
                                                          int* __restrict__ bcursor,
                                                          int2* __restrict__ pairs, int E) {
    __shared__ int cnt[BSIZE];
    __shared__ int base[BSIZE];
    for (int i = threadIdx.x; i < BSIZE; i += THREADS) cnt[i] = 0;
    __syncthreads();
    int e0 = blockIdx.x * 2048;
    int myb[8], myrank[8], mysrc[8], mydst[8];
#pragma unroll
    for (int j = 0; j < 8; ++j) {
        int e = e0 + j * THREADS + threadIdx.x;
        myb[j] = -1;
        if (e < E) {
            int d = dst[e];
            mysrc[j] = src[e];
            mydst[j] = d;
            myb[j] = d >> BSHIFT;
            myrank[j] = atomicAdd(&cnt[myb[j]], 1);
        }
    }
    __syncthreads();
    for (int i = threadIdx.x; i < BSIZE; i += THREADS) {
        int c = cnt[i];
        base[i] = c ? atomicAdd(&bcursor[i], c) : 0;
    }
    __syncthreads();
#pragma unroll
    for (int j = 0; j < 8; ++j)
        if (myb[j] >= 0) pairs[(size_t)base[myb[j]] + myrank[j]] = make_int2(mysrc[j], mydst[j]);
}

// one block per bucket: local count/scan -> row_start+dinv; local cursor -> esrc.
__global__ __launch_bounds__(512) void bucket_fill(const int2* __restrict__ pairs,
                                                   const int* __restrict__ bbase,
                                                   int* __restrict__ row_start,
                                                   float* __restrict__ dinv,
                                                   int* __restrict__ esrc,
                                                   int N, int E, int nbuck) {
    __shared__ int cnt[BSIZE];
    __shared__ int scn[BSIZE];
    int b = blockIdx.x, t = threadIdx.x;
    int s = bbase[b], e = bbase[b + 1];
    cnt[t] = 0;
    __syncthreads();
    for (int i = s + t; i < e; i += 512) atomicAdd(&cnt[pairs[i].y & (BSIZE - 1)], 1);
    __syncthreads();
    int v = cnt[t];
    scn[t] = v;
    __syncthreads();
    for (int off = 1; off < 512; off <<= 1) {
        int tv = (t >= off) ? scn[t - off] : 0;
        __syncthreads();
        scn[t] += tv;
        __syncthreads();
    }
    int excl = scn[t] - v;
    int g = (b << BSHIFT) + t;
    if (g < N) {
        row_start[g] = s + excl;
        dinv[g] = rsqrtf(1.0f + (float)v);  // deg = 1 + in-degree (self-loop)
    }
    if (b == nbuck - 1 && t == 0) row_start[N] = E;
    scn[t] = excl;  // reuse as cursor
    __syncthreads();
    for (int i = s + t; i < e; i += 512) {
        int2 p = pairs[i];
        int r = atomicAdd(&scn[p.y & (BSIZE - 1)], 1);
        esrc[s + r] = p.x;
    }
}

// ---- GEMM: Hs[n x C](bf16) = (X[n x 128] @ W[128 x C]) * dinv[row] ---------
template <int C>
__global__ __launch_bounds__(THREADS) void gemm_kernel(const float* __restrict__ X,
                                                       const float* __restrict__ W,
                                                       const float* __restrict__ dinv,
                                                       unsigned* __restrict__ Hs, int n) {
    constexpr int CG = C / 8;     // col groups (8 contiguous cols each): 16 or 8
    constexpr int RG = 256 / CG;  // row groups: 16 or 32
    constexpr int R = 64 / RG;    // rows per thread: 4 or 2
    __shared__ float Xs[64][36];  // 32-k tile, pad to 36
    __shared__ float Ws[32][C];
    int row0 = blockIdx.x * 64;
    int maxr = n - row0;
    if (maxr > 64) maxr = 64;
    int cg = threadIdx.x % CG;
    int rg = threadIdx.x / CG;
    float acc[R][8];
#pragma unroll
    for (int r = 0; r < R; ++r)
#pragma unroll
        for (int j = 0; j < 8; ++j) acc[r][j] = 0.0f;

    for (int kt = 0; kt < 4; ++kt) {
        if (kt) __syncthreads();
        const float* Xbase = X + (size_t)row0 * 128 + kt * 32;
        for (int i = threadIdx.x; i < 512; i += THREADS) {
            int r = i >> 3, f = i & 7;
            float4 v = make_float4(0.f, 0.f, 0.f, 0.f);
            if (r < maxr) v = *(const float4*)(Xbase + (size_t)r * 128 + f * 4);
            *(float4*)&Xs[r][f * 4] = v;
        }
        const float4* Wbase = (const float4*)(W + (size_t)kt * 32 * C);
        for (int i = threadIdx.x; i < 32 * C / 4; i += THREADS)
            ((float4*)&Ws[0][0])[i] = Wbase[i];
        __syncthreads();
#pragma unroll
        for (int kk = 0; kk < 32; kk += 4) {
            float4 xr[R];
#pragma unroll
            for (int r = 0; r < R; ++r) xr[r] = *(const float4*)&Xs[rg * R + r][kk];
#pragma unroll
            for (int j = 0; j < 4; ++j) {
                float4 w0 = *(const float4*)&Ws[kk + j][cg * 8];
                float4 w1 = *(const float4*)&Ws[kk + j][cg * 8 + 4];
#pragma unroll
                for (int r = 0; r < R; ++r) {
                    float xv = (&xr[r].x)[j];
                    acc[r][0] = fmaf(xv, w0.x, acc[r][0]);
                    acc[r][1] = fmaf(xv, w0.y, acc[r][1]);
                    acc[r][2] = fmaf(xv, w0.z, acc[r][2]);
                    acc[r][3] = fmaf(xv, w0.w, acc[r][3]);
                    acc[r][4] = fmaf(xv, w1.x, acc[r][4]);
                    acc[r][5] = fmaf(xv, w1.y, acc[r][5]);
                    acc[r][6] = fmaf(xv, w1.z, acc[r][6]);
                    acc[r][7] = fmaf(xv, w1.w, acc[r][7]);
                }
            }
        }
    }
#pragma unroll
    for (int r = 0; r < R; ++r) {
        int row = rg * R + r;
        if (row < maxr) {
            float dv = dinv[row0 + row];
            uint4 o;
            o.x = f2bf(acc[r][0] * dv) | (f2bf(acc[r][1] * dv) << 16);
            o.y = f2bf(acc[r][2] * dv) | (f2bf(acc[r][3] * dv) << 16);
            o.z = f2bf(acc[r][4] * dv) | (f2bf(acc[r][5] * dv) << 16);
            o.w = f2bf(acc[r][6] * dv) | (f2bf(acc[r][7] * dv) << 16);
            ((uint4*)Hs)[(size_t)(row0 + row) * (C / 8) + cg] = o;
        }
    }
}

// ---- agg: out[i] = dinv[i]*(sum Hs[src] + Hs[i]) + b (fp32 out) ------------
template <int C, bool RELU>
__global__ __launch_bounds__(THREADS) void agg_kernel(const unsigned* __restrict__ Hs,
                                                      const int* __restrict__ row_start,
                                                      const int* __restrict__ esrc,
                                                      const float* __restrict__ dinv,
                                                      const float* __restrict__ bias,
                                                      float* __restrict__ out, int n) {
    constexpr int LPN = C / 8;          // lanes per node (8 bf16 ch per lane)
    constexpr int NPB = THREADS / LPN;  // nodes per block
    int node = blockIdx.x * NPB + threadIdx.x / LPN;
    int lane = threadIdx.x % LPN;
    if (node >= n) return;
    const uint4* H4 = (const uint4*)Hs;
    float di = dinv[node];
    int s = row_start[node], e = row_start[node + 1];
    float ac[8] = {0, 0, 0, 0, 0, 0, 0, 0};
    bf8_acc(H4[(size_t)node * LPN + lane], ac);  // self term
    int i = s;
    for (; i + 8 <= e; i += 8) {
        int s0 = esrc[i], s1 = esrc[i + 1], s2 = esrc[i + 2], s3 = esrc[i + 3];
        int s4 = esrc[i + 4], s5 = esrc[i + 5], s6 = esrc[i + 6], s7 = esrc[i + 7];
        uint4 v0 = H4[(size_t)s0 * LPN + lane];
        uint4 v1 = H4[(size_t)s1 * LPN + lane];
        uint4 v2 = H4[(size_t)s2 * LPN + lane];
        uint4 v3 = H4[(size_t)s3 * LPN + lane];
        uint4 v4 = H4[(size_t)s4 * LPN + lane];
        uint4 v5 = H4[(size_t)s5 * LPN + lane];
        uint4 v6 = H4[(size_t)s6 * LPN + lane];
        uint4 v7 = H4[(size_t)s7 * LPN + lane];
        bf8_acc(v0, ac); bf8_acc(v1, ac); bf8_acc(v2, ac); bf8_acc(v3, ac);
        bf8_acc(v4, ac); bf8_acc(v5, ac); bf8_acc(v6, ac); bf8_acc(v7, ac);
    }
    for (; i + 4 <= e; i += 4) {
        int s0 = esrc[i], s1 = esrc[i + 1], s2 = esrc[i + 2], s3 = esrc[i + 3];
        uint4 v0 = H4[(size_t)s0 * LPN + lane];
        uint4 v1 = H4[(size_t)s1 * LPN + lane];
        uint4 v2 = H4[(size_t)s2 * LPN + lane];
        uint4 v3 = H4[(size_t)s3 * LPN + lane];
        bf8_acc(v0, ac); bf8_acc(v1, ac); bf8_acc(v2, ac); bf8_acc(v3, ac);
    }
    for (; i < e; ++i) bf8_acc(H4[(size_t)esrc[i] * LPN + lane], ac);

    float4 b0 = ((const float4*)bias)[lane * 2];
    float4 b1 = ((const float4*)bias)[lane * 2 + 1];
    float4 o0, o1;
    o0.x = fmaf(di, ac[0], b0.x); o0.y = fmaf(di, ac[1], b0.y);
    o0.z = fmaf(di, ac[2], b0.z); o0.w = fmaf(di, ac[3], b0.w);
    o1.x = fmaf(di, ac[4], b1.x); o1.y = fmaf(di, ac[5], b1.y);
    o1.z = fmaf(di, ac[6], b1.z); o1.w = fmaf(di, ac[7], b1.w);
    if (RELU) {
        o0.x = fmaxf(o0.x, 0.f); o0.y = fmaxf(o0.y, 0.f);
        o0.z = fmaxf(o0.z, 0.f); o0.w = fmaxf(o0.w, 0.f);
        o1.x = fmaxf(o1.x, 0.f); o1.y = fmaxf(o1.y, 0.f);
        o1.z = fmaxf(o1.z, 0.f); o1.w = fmaxf(o1.w, 0.f);
    }
    float4* O = (float4*)out;
    O[(size_t)node * (C / 4) + lane * 2] = o0;
    O[(size_t)node * (C / 4) + lane * 2 + 1] = o1;
}

// ---- two-stage pool + fused FC --------------------------------------------
#define PCHUNK 512

// stage 1: each block owns PCHUNK contiguous nodes; 16 node-streams x 16
// float4-lanes; register-accumulate per run of equal graph id (batch sorted),
// flush to gsum with atomics only at graph transitions.
__global__ __launch_bounds__(THREADS) void pool1_kernel(const float* __restrict__ H3,
                                                        const int* __restrict__ batch, int n,
                                                        float* __restrict__ gsum) {
    int base = blockIdx.x * PCHUNK;
    int lane = threadIdx.x & 15;   // channel group (4 ch)
    int sub = threadIdx.x >> 4;    // node stream
    const float4* H4 = (const float4*)H3;
    float4 acc = make_float4(0.f, 0.f, 0.f, 0.f);
    int cur_g = -1;
    int end = min(base + PCHUNK, n);
    for (int i = base + sub; i < end; i += 16) {
        int g = batch[i];
        if (g != cur_g) {
            if (cur_g >= 0) {
                float* p = gsum + cur_g * 64 + lane * 4;
                atomicAdd(p + 0, acc.x); atomicAdd(p + 1, acc.y);
                atomicAdd(p + 2, acc.z); atomicAdd(p + 3, acc.w);
                acc = make_float4(0.f, 0.f, 0.f, 0.f);
            }
            cur_g = g;
        }
        float4 v = H4[(size_t)i * 16 + lane];
        acc.x += v.x; acc.y += v.y; acc.z += v.z; acc.w += v.w;
    }
    if (cur_g >= 0) {
        float* p = gsum + cur_g * 64 + lane * 4;
        atomicAdd(p + 0, acc.x); atomicAdd(p + 1, acc.y);
        atomicAdd(p + 2, acc.z); atomicAdd(p + 3, acc.w);
    }
}

__device__ __forceinline__ int dev_lower_bound(const int* a, int n, int key) {
    int lo = 0, hi = n;
    while (lo < hi) {
        int mid = (lo + hi) >> 1;
        if (a[mid] < key) lo = mid + 1;
        else hi = mid;
    }
    return lo;
}

// stage 2: gmean = gsum / cnt(g), then out = gmean @ Wfc + bfc. One block.
__global__ __launch_bounds__(128) void finalize_fc(const float* __restrict__ gsum,
                                                   const int* __restrict__ batch, int n,
                                                   const float* __restrict__ Wfc,
                                                   const float* __restrict__ bfc,
                                                   float* __restrict__ out) {
    __shared__ float gm[64 * 64];
    __shared__ float cnt[64];
    int t = threadIdx.x;
    if (t < 64)
        cnt[t] = (float)(dev_lower_bound(batch, n, t + 1) - dev_lower_bound(batch, n, t));
    __syncthreads();
    for (int i = t; i < 64 * 64; i += 128) gm[i] = gsum[i] / fmaxf(cnt[i >> 6], 1.0f);
    __syncthreads();
    int g = t >> 1, cls = t & 1;
    float acc = bfc[cls];
    for (int c = 0; c < 64; ++c) acc = fmaf(gm[g * 64 + c], Wfc[c * 2 + cls], acc);
    out[g * 2 + cls] = acc;
}

extern "C" void kernel_launch(void* const* d_in, const int* in_sizes, int n_in,
                              void* d_out, int out_size, void* d_ws, size_t ws_size,
                              hipStream_t stream) {
    const float* x    = (const float*)d_in[0];
    const int*   ei   = (const int*)d_in[1];
    const int*   batch= (const int*)d_in[2];
    const float* W1   = (const float*)d_in[3];
    const float* b1   = (const float*)d_in[4];
    const float* W2   = (const float*)d_in[5];
    const float* b2   = (const float*)d_in[6];
    const float* W3   = (const float*)d_in[7];
    const float* b3   = (const float*)d_in[8];
    const float* Wfc  = (const float*)d_in[9];
    const float* bfc  = (const float*)d_in[10];
    float* out = (float*)d_out;

    const int N = in_sizes[2];        // 100000
    const int E = in_sizes[1] / 2;    // 1600000
    const int* esrc_in = ei;          // edge_index[0]
    const int* edst_in = ei + E;      // edge_index[1]
    const int nbuck = (N + BSIZE - 1) >> BSHIFT;  // 196

    // workspace layout
    float*    bufA      = (float*)d_ws;                        // N*128 f32
    unsigned* bufH      = (unsigned*)(bufA + (size_t)N * 128); // N*64 uints (bf16 x2)
    int2*     pairs     = (int2*)(bufH + (size_t)N * 64);      // E
    int*      esrc      = (int*)(pairs + E);                   // E
    int*      row_start = esrc + E;                            // N+1
    float*    dinv      = (float*)(row_start + N + 1);         // N
    int*      btotal    = (int*)(dinv + N);                    // 512
    int*      bbase     = btotal + 512;                        // 513
    int*      bcursor   = bbase + 513;                         // 512
    float*    gsum      = (float*)(bcursor + 512);             // 64*64

    // ---- bucketed CSR build (once; reused by all 3 layers) ----
    zero_btotal<<<1, 512, 0, stream>>>(btotal, nbuck);
    zero_f32<<<16, THREADS, 0, stream>>>(gsum, 64 * 64);
    bucket_count<<<512, THREADS, 0, stream>>>(edst_in, btotal, E, nbuck);
    bucket_scan<<<1, 512, 0, stream>>>(btotal, bbase, bcursor, nbuck, E);
    bucket_scatter<<<(E + 2047) / 2048, THREADS, 0, stream>>>(esrc_in, edst_in, bcursor, pairs, E);
    bucket_fill<<<nbuck, 512, 0, stream>>>(pairs, bbase, row_start, dinv, esrc, N, E, nbuck);

    const int GB = (N + 63) / 64;

    // ---- layer 1 ----
    gemm_kernel<128><<<GB, THREADS, 0, stream>>>(x, W1, dinv, bufH, N);
    agg_kernel<128, true><<<(N + 15) / 16, THREADS, 0, stream>>>(bufH, row_start, esrc, dinv, b1, bufA, N);

    // ---- layer 2 ----
    gemm_kernel<128><<<GB, THREADS, 0, stream>>>(bufA, W2, dinv, bufH, N);
    agg_kernel<128, true><<<(N + 15) / 16, THREADS, 0, stream>>>(bufH, row_start, esrc, dinv, b2, bufA, N);

    // ---- layer 3 (C=64, no relu) ----
    gemm_kernel<64><<<GB, THREADS, 0, stream>>>(bufA, W3, dinv, bufH, N);
    agg_kernel<64, false><<<(N + 31) / 32, THREADS, 0, stream>>>(bufH, row_start, esrc, dinv, b3, bufA, N);

    // ---- two-stage pool + fused fc ----
    pool1_kernel<<<(N + PCHUNK - 1) / PCHUNK, THREADS, 0, stream>>>(bufA, batch, N, gsum);
    finalize_fc<<<1, 128, 0, stream>>>(gsum, batch, N, Wfc, bfc, out);
}

// Round 5
// 437.307 us; speedup vs baseline: 3.1500x; 1.1800x over previous
//
#include <hip/hip_runtime.h>
#include <hip/hip_bf16.h>

// ---------------------------------------------------------------------------
// GCN: 3x [Hs = bf16((X@W)*dinv) via MFMA ; out = bf16(dinv*(sum Hs[src] + Hs[i]) + b);
//          (ReLU)] -> mean-pool -> FC 64->2
// R5: MFMA GEMM (32x32x16 bf16, D = W^T X^T so lanes own node-rows; swizzled
//     LDS; coalesced bf16 out). agg outputs packed bf16. W pre-transposed once.
// ---------------------------------------------------------------------------

#define THREADS 256
#define BSHIFT 9
#define BSIZE 512

typedef __attribute__((ext_vector_type(8))) short short8;
typedef __attribute__((ext_vector_type(16))) float floatx16;

__device__ __forceinline__ unsigned f2bf(float f) {  // fp32 -> bf16 bits, RNE
    unsigned u = __float_as_uint(f);
    return (u + 0x7fffu + ((u >> 16) & 1u)) >> 16;
}

__device__ __forceinline__ void bf8_acc(uint4 v, float* ac) {
    ac[0] += __uint_as_float(v.x << 16);
    ac[1] += __uint_as_float(v.x & 0xffff0000u);
    ac[2] += __uint_as_float(v.y << 16);
    ac[3] += __uint_as_float(v.y & 0xffff0000u);
    ac[4] += __uint_as_float(v.z << 16);
    ac[5] += __uint_as_float(v.z & 0xffff0000u);
    ac[6] += __uint_as_float(v.w << 16);
    ac[7] += __uint_as_float(v.w & 0xffff0000u);
}

// ---- bucketed CSR build ----------------------------------------------------

__global__ __launch_bounds__(512) void zero_btotal(int* btotal, int nbuck) {
    if ((int)threadIdx.x < nbuck) btotal[threadIdx.x] = 0;
}

__global__ __launch_bounds__(THREADS) void zero_f32(float* p, int n) {
    int i = blockIdx.x * THREADS + threadIdx.x;
    if (i < n) p[i] = 0.0f;
}

__global__ __launch_bounds__(THREADS) void bucket_count(const int* __restrict__ dst,
                                                        int* __restrict__ btotal,
                                                        int E, int nbuck) {
    __shared__ int cnt[BSIZE];
    for (int i = threadIdx.x; i < nbuck; i += THREADS) cnt[i] = 0;
    __syncthreads();
    for (int e = blockIdx.x * THREADS + threadIdx.x; e < E; e += gridDim.x * THREADS)
        atomicAdd(&cnt[dst[e] >> BSHIFT], 1);
    __syncthreads();
    for (int i = threadIdx.x; i < nbuck; i += THREADS) {
        int c = cnt[i];
        if (c) atomicAdd(&btotal[i], c);
    }
}

__global__ __launch_bounds__(512) void bucket_scan(const int* __restrict__ btotal,
                                                   int* __restrict__ bbase,
                                                   int* __restrict__ bcursor,
                                                   int nbuck, int E) {
    __shared__ int lds[512];
    int t = threadIdx.x;
    int v = (t < nbuck) ? btotal[t] : 0;
    lds[t] = v;
    __syncthreads();
    for (int off = 1; off < 512; off <<= 1) {
        int tv = (t >= off) ? lds[t - off] : 0;
        __syncthreads();
        lds[t] += tv;
        __syncthreads();
    }
    if (t < nbuck) {
        int excl = lds[t] - v;
        bbase[t] = excl;
        bcursor[t] = excl;
    }
    if (t == 0) bbase[nbuck] = E;
}

__global__ __launch_bounds__(THREADS) void bucket_scatter(const int* __restrict__ src,
                                                          const int* __restrict__ dst,
                                                          int* __restrict__ bcursor,
                                                          int2* __restrict__ pairs, int E) {
    __shared__ int cnt[BSIZE];
    __shared__ int base[BSIZE];
    for (int i = threadIdx.x; i < BSIZE; i += THREADS) cnt[i] = 0;
    __syncthreads();
    int e0 = blockIdx.x * 2048;
    int myb[8], myrank[8], mysrc[8], mydst[8];
#pragma unroll
    for (int j = 0; j < 8; ++j) {
        int e = e0 + j * THREADS + threadIdx.x;
        myb[j] = -1;
        if (e < E) {
            int d = dst[e];
            mysrc[j] = src[e];
            mydst[j] = d;
            myb[j] = d >> BSHIFT;
            myrank[j] = atomicAdd(&cnt[myb[j]], 1);
        }
    }
    __syncthreads();
    for (int i = threadIdx.x; i < BSIZE; i += THREADS) {
        int c = cnt[i];
        base[i] = c ? atomicAdd(&bcursor[i], c) : 0;
    }
    __syncthreads();
#pragma unroll
    for (int j = 0; j < 8; ++j)
        if (myb[j] >= 0) pairs[(size_t)base[myb[j]] + myrank[j]] = make_int2(mysrc[j], mydst[j]);
}

__global__ __launch_bounds__(512) void bucket_fill(const int2* __restrict__ pairs,
                                                   const int* __restrict__ bbase,
                                                   int* __restrict__ row_start,
                                                   float* __restrict__ dinv,
                                                   int* __restrict__ esrc,
                                                   int N, int E, int nbuck) {
    __shared__ int cnt[BSIZE];
    __shared__ int scn[BSIZE];
    int b = blockIdx.x, t = threadIdx.x;
    int s = bbase[b], e = bbase[b + 1];
    cnt[t] = 0;
    __syncthreads();
    for (int i = s + t; i < e; i += 512) atomicAdd(&cnt[pairs[i].y & (BSIZE - 1)], 1);
    __syncthreads();
    int v = cnt[t];
    scn[t] = v;
    __syncthreads();
    for (int off = 1; off < 512; off <<= 1) {
        int tv = (t >= off) ? scn[t - off] : 0;
        __syncthreads();
        scn[t] += tv;
        __syncthreads();
    }
    int excl = scn[t] - v;
    int g = (b << BSHIFT) + t;
    if (g < N) {
        row_start[g] = s + excl;
        dinv[g] = rsqrtf(1.0f + (float)v);  // deg = 1 + in-degree (self-loop)
    }
    if (b == nbuck - 1 && t == 0) row_start[N] = E;
    scn[t] = excl;  // reuse as cursor
    __syncthreads();
    for (int i = s + t; i < e; i += 512) {
        int2 p = pairs[i];
        int r = atomicAdd(&scn[p.y & (BSIZE - 1)], 1);
        esrc[s + r] = p.x;
    }
}

// ---- W prep: Wt[c][k] packed bf16 (uint4 = 8 k-values) ---------------------
__global__ __launch_bounds__(THREADS) void prep_wt(const float* __restrict__ W,
                                                   uint4* __restrict__ Wtp, int C) {
    int idx = blockIdx.x * THREADS + threadIdx.x;  // c*16 + kchunk
    if (idx >= C * 16) return;
    int c = idx >> 4, ch = idx & 15;
    unsigned r[8];
#pragma unroll
    for (int j = 0; j < 8; ++j) r[j] = f2bf(W[(size_t)(ch * 8 + j) * C + c]);
    uint4 o;
    o.x = r[0] | (r[1] << 16);
    o.y = r[2] | (r[3] << 16);
    o.z = r[4] | (r[5] << 16);
    o.w = r[6] | (r[7] << 16);
    Wtp[idx] = o;
}

// ---- MFMA GEMM: Hs[n x C](bf16) = bf16((X@W)) * dinv[row] ------------------
// D = W^T * X^T via mfma_f32_32x32x16_bf16: lane owns one node, regs = channels.
// LDS chunks (16B = 8 bf16 along k) XOR-swizzled by (row&7) for uniform banks.
template <int C, bool IN_F32>
__global__ __launch_bounds__(THREADS) void gemm_mfma(const void* __restrict__ Xin,
                                                     const uint4* __restrict__ Wt,
                                                     const float* __restrict__ dinv,
                                                     uint4* __restrict__ Hs, int n) {
    __shared__ __align__(16) char lds_raw[16384 + C * 256];  // Xs[64][16ch] + Wst[C][16ch]
    int row0 = blockIdx.x * 64;
    int maxr = n - row0;
    if (maxr > 64) maxr = 64;
    int tid = threadIdx.x;

    // stage X: 64 rows x 16 chunks
    if (IN_F32) {
        const float* X = (const float*)Xin;
        for (int idx = tid; idx < 1024; idx += THREADS) {
            int r = idx >> 4, c = idx & 15;
            uint4 o = make_uint4(0, 0, 0, 0);
            if (r < maxr) {
                const float* p = X + (size_t)(row0 + r) * 128 + c * 8;
                float4 a = *(const float4*)p;
                float4 b = *(const float4*)(p + 4);
                o.x = f2bf(a.x) | (f2bf(a.y) << 16);
                o.y = f2bf(a.z) | (f2bf(a.w) << 16);
                o.z = f2bf(b.x) | (f2bf(b.y) << 16);
                o.w = f2bf(b.z) | (f2bf(b.w) << 16);
            }
            *(uint4*)(lds_raw + r * 256 + ((c ^ (r & 7)) * 16)) = o;
        }
    } else {
        const uint4* X = (const uint4*)Xin;  // packed bf16, 16 chunks/row
        for (int idx = tid; idx < 1024; idx += THREADS) {
            int r = idx >> 4, c = idx & 15;
            uint4 o = (r < maxr) ? X[(size_t)(row0 + r) * 16 + c] : make_uint4(0, 0, 0, 0);
            *(uint4*)(lds_raw + r * 256 + ((c ^ (r & 7)) * 16)) = o;
        }
    }
    // stage Wt: C rows x 16 chunks
    for (int idx = tid; idx < C * 16; idx += THREADS) {
        int cc = idx >> 4, c = idx & 15;
        *(uint4*)(lds_raw + 16384 + cc * 256 + ((c ^ (cc & 7)) * 16)) = Wt[idx];
    }
    __syncthreads();

    int wave = tid >> 6, lane = tid & 63;
    int l31 = lane & 31, half = lane >> 5;
    constexpr int MT = (C == 128) ? 2 : 1;  // channel tiles per wave
    int nt = wave & 1;                       // node tile
    int mt0 = (C == 128) ? ((wave >> 1) * 2) : (wave >> 1);
    floatx16 acc[MT];
#pragma unroll
    for (int t = 0; t < MT; ++t)
#pragma unroll
        for (int q = 0; q < 16; ++q) acc[t][q] = 0.0f;

    int xrow = nt * 32 + l31;
    const char* xbase = lds_raw + xrow * 256;
    int xsw = xrow & 7;
    const char* wbase[MT];
    int wsw[MT];
#pragma unroll
    for (int t = 0; t < MT; ++t) {
        int wrow = (mt0 + t) * 32 + l31;
        wbase[t] = lds_raw + 16384 + wrow * 256;
        wsw[t] = wrow & 7;
    }
#pragma unroll
    for (int kt = 0; kt < 8; ++kt) {
        int chunk = kt * 2 + half;
        short8 xf = *(const short8*)(xbase + ((chunk ^ xsw) * 16));
#pragma unroll
        for (int t = 0; t < MT; ++t) {
            short8 wf = *(const short8*)(wbase[t] + ((chunk ^ wsw[t]) * 16));
            acc[t] = __builtin_amdgcn_mfma_f32_32x32x16_bf16(wf, xf, acc[t], 0, 0, 0);
        }
    }
    __syncthreads();

    // epilogue: lane = node (nt*32+l31); acc[t][reg] = channel (mt0+t)*32 + (reg&3)+8*(reg>>2)+4*half
    int node = nt * 32 + l31;
    float dv = (node < maxr) ? dinv[row0 + node] : 0.0f;
    char* outb = lds_raw;  // alias over Xs region: 64 rows x C*2 bytes
#pragma unroll
    for (int t = 0; t < MT; ++t) {
        int cbase = (mt0 + t) * 32;
#pragma unroll
        for (int q = 0; q < 4; ++q) {
            unsigned p0 = f2bf(acc[t][q * 4 + 0] * dv) | (f2bf(acc[t][q * 4 + 1] * dv) << 16);
            unsigned p1 = f2bf(acc[t][q * 4 + 2] * dv) | (f2bf(acc[t][q * 4 + 3] * dv) << 16);
            int chunk = (cbase >> 3) + q;  // 8 channels per chunk
            uint2 pk = make_uint2(p0, p1);
            *(uint2*)(outb + node * (C * 2) + ((chunk ^ (node & 7)) * 16) + half * 8) = pk;
        }
    }
    __syncthreads();
    // coalesced store
    constexpr int RCH = C / 8;  // uint4 chunks per row
    for (int idx = tid; idx < maxr * RCH; idx += THREADS) {
        int r = idx / RCH, c = idx % RCH;
        uint4 v = *(const uint4*)(outb + r * (C * 2) + ((c ^ (r & 7)) * 16));
        Hs[(size_t)(row0 + r) * RCH + c] = v;
    }
}

// ---- agg: out[i] = bf16(dinv[i]*(sum Hs[src] + Hs[i]) + b), packed bf16 ----
template <int C, bool RELU>
__global__ __launch_bounds__(THREADS) void agg_kernel(const unsigned* __restrict__ Hs,
                                                      const int* __restrict__ row_start,
                                                      const int* __restrict__ esrc,
                                                      const float* __restrict__ dinv,
                                                      const float* __restrict__ bias,
                                                      unsigned* __restrict__ out, int n) {
    constexpr int LPN = C / 8;          // lanes per node (8 bf16 ch per lane)
    constexpr int NPB = THREADS / LPN;  // nodes per block
    int node = blockIdx.x * NPB + threadIdx.x / LPN;
    int lane = threadIdx.x % LPN;
    if (node >= n) return;
    const uint4* H4 = (const uint4*)Hs;
    float di = dinv[node];
    int s = row_start[node], e = row_start[node + 1];
    float ac[8] = {0, 0, 0, 0, 0, 0, 0, 0};
    bf8_acc(H4[(size_t)node * LPN + lane], ac);  // self term
    int i = s;
    for (; i + 8 <= e; i += 8) {
        int s0 = esrc[i], s1 = esrc[i + 1], s2 = esrc[i + 2], s3 = esrc[i + 3];
        int s4 = esrc[i + 4], s5 = esrc[i + 5], s6 = esrc[i + 6], s7 = esrc[i + 7];
        uint4 v0 = H4[(size_t)s0 * LPN + lane];
        uint4 v1 = H4[(size_t)s1 * LPN + lane];
        uint4 v2 = H4[(size_t)s2 * LPN + lane];
        uint4 v3 = H4[(size_t)s3 * LPN + lane];
        uint4 v4 = H4[(size_t)s4 * LPN + lane];
        uint4 v5 = H4[(size_t)s5 * LPN + lane];
        uint4 v6 = H4[(size_t)s6 * LPN + lane];
        uint4 v7 = H4[(size_t)s7 * LPN + lane];
        bf8_acc(v0, ac); bf8_acc(v1, ac); bf8_acc(v2, ac); bf8_acc(v3, ac);
        bf8_acc(v4, ac); bf8_acc(v5, ac); bf8_acc(v6, ac); bf8_acc(v7, ac);
    }
    for (; i + 4 <= e; i += 4) {
        int s0 = esrc[i], s1 = esrc[i + 1], s2 = esrc[i + 2], s3 = esrc[i + 3];
        uint4 v0 = H4[(size_t)s0 * LPN + lane];
        uint4 v1 = H4[(size_t)s1 * LPN + lane];
        uint4 v2 = H4[(size_t)s2 * LPN + lane];
        uint4 v3 = H4[(size_t)s3 * LPN + lane];
        bf8_acc(v0, ac); bf8_acc(v1, ac); bf8_acc(v2, ac); bf8_acc(v3, ac);
    }
    for (; i < e; ++i) bf8_acc(H4[(size_t)esrc[i] * LPN + lane], ac);

    float4 b0 = ((const float4*)bias)[lane * 2];
    float4 b1 = ((const float4*)bias)[lane * 2 + 1];
    float o_[8];
    o_[0] = fmaf(di, ac[0], b0.x); o_[1] = fmaf(di, ac[1], b0.y);
    o_[2] = fmaf(di, ac[2], b0.z); o_[3] = fmaf(di, ac[3], b0.w);
    o_[4] = fmaf(di, ac[4], b1.x); o_[5] = fmaf(di, ac[5], b1.y);
    o_[6] = fmaf(di, ac[6], b1.z); o_[7] = fmaf(di, ac[7], b1.w);
    if (RELU) {
#pragma unroll
        for (int j = 0; j < 8; ++j) o_[j] = fmaxf(o_[j], 0.0f);
    }
    uint4 o;
    o.x = f2bf(o_[0]) | (f2bf(o_[1]) << 16);
    o.y = f2bf(o_[2]) | (f2bf(o_[3]) << 16);
    o.z = f2bf(o_[4]) | (f2bf(o_[5]) << 16);
    o.w = f2bf(o_[6]) | (f2bf(o_[7]) << 16);
    ((uint4*)out)[(size_t)node * LPN + lane] = o;
}

// ---- two-stage pool + fused FC --------------------------------------------
#define PCHUNK 512

// stage 1: bf16 packed input (64 ch = 8 chunks). 32 node streams x 8 chunk lanes.
__global__ __launch_bounds__(THREADS) void pool1_kernel(const unsigned* __restrict__ H3,
                                                        const int* __restrict__ batch, int n,
                                                        float* __restrict__ gsum) {
    int base = blockIdx.x * PCHUNK;
    int lane = threadIdx.x & 7;   // chunk (8 ch)
    int sub = threadIdx.x >> 3;   // node stream
    const uint4* H4 = (const uint4*)H3;
    float ac[8] = {0, 0, 0, 0, 0, 0, 0, 0};
    int cur_g = -1;
    int end = min(base + PCHUNK, n);
    for (int i = base + sub; i < end; i += 32) {
        int g = batch[i];
        if (g != cur_g) {
            if (cur_g >= 0) {
                float* p = gsum + cur_g * 64 + lane * 8;
#pragma unroll
                for (int j = 0; j < 8; ++j) atomicAdd(p + j, ac[j]);
#pragma unroll
                for (int j = 0; j < 8; ++j) ac[j] = 0.0f;
            }
            cur_g = g;
        }
        bf8_acc(H4[(size_t)i * 8 + lane], ac);
    }
    if (cur_g >= 0) {
        float* p = gsum + cur_g * 64 + lane * 8;
#pragma unroll
        for (int j = 0; j < 8; ++j) atomicAdd(p + j, ac[j]);
    }
}

__device__ __forceinline__ int dev_lower_bound(const int* a, int n, int key) {
    int lo = 0, hi = n;
    while (lo < hi) {
        int mid = (lo + hi) >> 1;
        if (a[mid] < key) lo = mid + 1;
        else hi = mid;
    }
    return lo;
}

__global__ __launch_bounds__(128) void finalize_fc(const float* __restrict__ gsum,
                                                   const int* __restrict__ batch, int n,
                                                   const float* __restrict__ Wfc,
                                                   const float* __restrict__ bfc,
                                                   float* __restrict__ out) {
    __shared__ float gm[64 * 64];
    __shared__ float cnt[64];
    int t = threadIdx.x;
    if (t < 64)
        cnt[t] = (float)(dev_lower_bound(batch, n, t + 1) - dev_lower_bound(batch, n, t));
    __syncthreads();
    for (int i = t; i < 64 * 64; i += 128) gm[i] = gsum[i] / fmaxf(cnt[i >> 6], 1.0f);
    __syncthreads();
    int g = t >> 1, cls = t & 1;
    float acc = bfc[cls];
    for (int c = 0; c < 64; ++c) acc = fmaf(gm[g * 64 + c], Wfc[c * 2 + cls], acc);
    out[g * 2 + cls] = acc;
}

extern "C" void kernel_launch(void* const* d_in, const int* in_sizes, int n_in,
                              void* d_out, int out_size, void* d_ws, size_t ws_size,
                              hipStream_t stream) {
    const float* x    = (const float*)d_in[0];
    const int*   ei   = (const int*)d_in[1];
    const int*   batch= (const int*)d_in[2];
    const float* W1   = (const float*)d_in[3];
    const float* b1   = (const float*)d_in[4];
    const float* W2   = (const float*)d_in[5];
    const float* b2   = (const float*)d_in[6];
    const float* W3   = (const float*)d_in[7];
    const float* b3   = (const float*)d_in[8];
    const float* Wfc  = (const float*)d_in[9];
    const float* bfc  = (const float*)d_in[10];
    float* out = (float*)d_out;

    const int N = in_sizes[2];        // 100000
    const int E = in_sizes[1] / 2;    // 1600000
    const int* esrc_in = ei;          // edge_index[0]
    const int* edst_in = ei + E;      // edge_index[1]
    const int nbuck = (N + BSIZE - 1) >> BSHIFT;  // 196

    // workspace layout
    unsigned* bufA      = (unsigned*)d_ws;                     // N*128 f32-sized; holds packed bf16 agg out
    unsigned* bufH      = bufA + (size_t)N * 128;              // N*64 uints: GEMM out packed bf16
    int2*     pairs     = (int2*)(bufH + (size_t)N * 64);      // E
    int*      esrc      = (int*)(pairs + E);                   // E
    int*      row_start = esrc + E;                            // N+1
    float*    dinv      = (float*)(row_start + N + 1);         // N
    int*      btotal    = (int*)(dinv + N);                    // 512
    int*      bbase     = btotal + 512;                        // 513
    int*      bcursor   = bbase + 513;                         // 512
    float*    gsum      = (float*)(bcursor + 512);             // 64*64
    uint4*    Wt1       = (uint4*)(gsum + 64 * 64);            // 2048 uint4
    uint4*    Wt2       = Wt1 + 2048;                          // 2048
    uint4*    Wt3       = Wt2 + 2048;                          // 1024

    // ---- prep: transpose+bf16 weights; CSR build; zero gsum ----
    prep_wt<<<8, THREADS, 0, stream>>>(W1, Wt1, 128);
    prep_wt<<<8, THREADS, 0, stream>>>(W2, Wt2, 128);
    prep_wt<<<4, THREADS, 0, stream>>>(W3, Wt3, 64);
    zero_btotal<<<1, 512, 0, stream>>>(btotal, nbuck);
    zero_f32<<<16, THREADS, 0, stream>>>(gsum, 64 * 64);
    bucket_count<<<512, THREADS, 0, stream>>>(edst_in, btotal, E, nbuck);
    bucket_scan<<<1, 512, 0, stream>>>(btotal, bbase, bcursor, nbuck, E);
    bucket_scatter<<<(E + 2047) / 2048, THREADS, 0, stream>>>(esrc_in, edst_in, bcursor, pairs, E);
    bucket_fill<<<nbuck, 512, 0, stream>>>(pairs, bbase, row_start, dinv, esrc, N, E, nbuck);

    const int GB = (N + 63) / 64;

    // ---- layer 1 ----
    gemm_mfma<128, true><<<GB, THREADS, 0, stream>>>(x, Wt1, dinv, (uint4*)bufH, N);
    agg_kernel<128, true><<<(N + 15) / 16, THREADS, 0, stream>>>(bufH, row_start, esrc, dinv, b1, bufA, N);

    // ---- layer 2 ----
    gemm_mfma<128, false><<<GB, THREADS, 0, stream>>>(bufA, Wt2, dinv, (uint4*)bufH, N);
    agg_kernel<128, true><<<(N + 15) / 16, THREADS, 0, stream>>>(bufH, row_start, esrc, dinv, b2, bufA, N);

    // ---- layer 3 (C=64, no relu) ----
    gemm_mfma<64, false><<<GB, THREADS, 0, stream>>>(bufA, Wt3, dinv, (uint4*)bufH, N);
    agg_kernel<64, false><<<(N + 31) / 32, THREADS, 0, stream>>>(bufH, row_start, esrc, dinv, b3, bufA, N);

    // ---- two-stage pool + fused fc ----
    pool1_kernel<<<(N + PCHUNK - 1) / PCHUNK, THREADS, 0, stream>>>(bufA, batch, N, gsum);
    finalize_fc<<<1, 128, 0, stream>>>(gsum, batch, N, Wfc, bfc, out);
}